// Round 1
// baseline (3116.789 us; speedup 1.0000x reference)
//
#include <hip/hip_runtime.h>
#include <stdint.h>

#define NKEYS 65536
#define DIM   1024
#define BQ    4096
#define DXV   768
#define DYV   256
#define THRESH 0.01f

#define BM 128
#define BN 128
#define BKB 128   // K-slice BYTES per tile step = 128 fp8 elements (row = 128 B, same as bf16 BK=64)

typedef __attribute__((ext_vector_type(4))) int   i32x4;
typedef __attribute__((ext_vector_type(8))) int   i32x8;
typedef __attribute__((ext_vector_type(4))) float f32x4;

__device__ __forceinline__ void gl2lds16(const void* g, void* l) {
  __builtin_amdgcn_global_load_lds(
      (const __attribute__((address_space(1))) unsigned int*)g,
      (__attribute__((address_space(3))) unsigned int*)l, 16, 0, 0);
}

__device__ __forceinline__ unsigned int orderf(float f) {
  unsigned int u = __float_as_uint(f);
  return (u & 0x80000000u) ? ~u : (u | 0x80000000u);
}

// ---------------- prep: keys fp32 -> fp8 e4m3 (OCP), fused fp32 row norms ----------------
// knorm stays EXACT fp32 (computed from original keys); only the -2*kq term is fp8.
__global__ void prep_keys(const float* __restrict__ keys,
                          unsigned int* __restrict__ K8,
                          float* __restrict__ knorm) {
  const int row = blockIdx.x;
  const int t = threadIdx.x;          // 256 threads, 4 floats -> 4 fp8 bytes each
  const float4 v = ((const float4*)(keys + (size_t)row * DIM))[t];
  unsigned int p = (unsigned int)__builtin_amdgcn_cvt_pk_fp8_f32(v.x, v.y, 0, false);
  p = (unsigned int)__builtin_amdgcn_cvt_pk_fp8_f32(v.z, v.w, (int)p, true);
  K8[(size_t)row * (DIM / 4) + t] = p;
  float s = v.x * v.x + v.y * v.y + v.z * v.z + v.w * v.w;
  for (int m = 32; m; m >>= 1) s += __shfl_xor(s, m);
  __shared__ float red[4];
  const int lane = t & 63, wave = t >> 6;
  if (lane == 0) red[wave] = s;
  __syncthreads();
  if (t == 0) knorm[row] = red[0] + red[1] + red[2] + red[3];
}

// ---------------- prep: q = concat(X, Y) -> fp8 e4m3 ----------------
__global__ void prep_q(const float* __restrict__ X, const float* __restrict__ Y,
                       unsigned int* __restrict__ Q8) {
  const int row = blockIdx.x;
  const int t = threadIdx.x;          // 256 threads
  float4 v;
  if (t < 192) v = ((const float4*)(X + (size_t)row * DXV))[t];
  else         v = ((const float4*)(Y + (size_t)row * DYV))[t - 192];
  unsigned int p = (unsigned int)__builtin_amdgcn_cvt_pk_fp8_f32(v.x, v.y, 0, false);
  p = (unsigned int)__builtin_amdgcn_cvt_pk_fp8_f32(v.z, v.w, (int)p, true);
  Q8[(size_t)row * (DIM / 4) + t] = p;   // X at dwords 0..191, Y at 192..255
}

// ---------------- main: MX-fp8 (scale=1.0) MFMA GEMM + fused argmin ----------------
// scores = knorm[n] - 2*dot(keys[n], q[b]); argmin_n per b via packed u64 atomicMin.
// mfma_scale_f32_16x16x128_f8f6f4 with e8m0 scales = 0x7F (exactly 1.0) runs at 2x the
// bf16 rate (non-scaled fp8 MFMA == bf16 rate on gfx950) and halves staging bytes.
// LDS layout identical to the verified bf16 kernel: rows are 128 B (now 128 fp8 instead
// of 64 bf16); 16B-chunk index XOR (row&7), pre-swizzled on the *global* source address
// (global_load_lds writes linearly), same XOR applied on reads -> measured 0 conflicts.
// Per-lane fragment = 32 contiguous k-bytes at row (lane&15), k-block (lane>>4)*32,
// fetched as two ds_read_b128 at XOR-adjacent chunks.
__global__ __launch_bounds__(256, 3) void gemm_argmin(
    const unsigned char* __restrict__ Kb,   // [NKEYS][DIM] fp8
    const unsigned char* __restrict__ Qb,   // [BQ][DIM] fp8
    const float* __restrict__ knorm,        // [NKEYS]
    unsigned long long* __restrict__ best) { // [BQ]
  __shared__ __align__(16) unsigned char As[BM * BKB];  // q tile [m][k]  16 KB
  __shared__ __align__(16) unsigned char Bs[BN * BKB];  // keys tile [n][k] 16 KB
  __shared__ unsigned long long cand[2][BM];

  const int bid = blockIdx.x;
  const int mtile = bid & 31;          // m-fastest: 32 blocks share a keys tile
  const int ntile = bid >> 5;
  const int tid = threadIdx.x;
  const int wave = tid >> 6;
  const int lane = tid & 63;
  const int wm = wave >> 1;
  const int wn = wave & 1;
  const int lr = lane & 15;
  const int quad = lane >> 4;

  // staging map: 16 chunks of 1KB per operand tile; wave w owns chunks 4w..4w+3
  const unsigned char* agl[4]; const unsigned char* bgl[4];
  void* aldst[4]; void* bldst[4];
#pragma unroll
  for (int c = 0; c < 4; ++c) {
    const int chunk = wave * 4 + c;
    const int off = chunk * 1024 + lane * 16;    // byte offset in 16KB tile
    const int r = off >> 7;                      // row (128 B per row)
    const int kb = (off & 127) ^ ((r & 7) * 16); // swizzled source byte col
    agl[c] = Qb + ((size_t)(mtile * BM + r) * DIM + kb);
    bgl[c] = Kb + ((size_t)(ntile * BN + r) * DIM + kb);
    aldst[c] = (void*)(As + chunk * 1024);
    bldst[c] = (void*)(Bs + chunk * 1024);
  }

  f32x4 acc[4][4];
#pragma unroll
  for (int i = 0; i < 4; ++i)
#pragma unroll
    for (int j = 0; j < 4; ++j) acc[i][j] = (f32x4)0.0f;

  const int swz = (lr & 7) * 16;                  // read-side chunk swizzle
  const int c0 = (quad * 32) ^ swz;               // first 16B of lane's 32B k-block
  const int c1 = (quad * 32 + 16) ^ swz;          // second 16B

  for (int kt = 0; kt < DIM / BKB; ++kt) {
    const size_t ko = (size_t)kt * BKB;
#pragma unroll
    for (int c = 0; c < 4; ++c) gl2lds16(agl[c] + ko, aldst[c]);
#pragma unroll
    for (int c = 0; c < 4; ++c) gl2lds16(bgl[c] + ko, bldst[c]);
    __syncthreads();

    i32x8 bf[4];
#pragma unroll
    for (int fn = 0; fn < 4; ++fn) {
      const int base = (wn * 64 + fn * 16 + lr) * BKB;
      const i32x4 lo = *(const i32x4*)(Bs + base + c0);
      const i32x4 hi = *(const i32x4*)(Bs + base + c1);
      bf[fn] = __builtin_shufflevector(lo, hi, 0, 1, 2, 3, 4, 5, 6, 7);
    }
#pragma unroll
    for (int fm = 0; fm < 4; ++fm) {
      const int base = (wm * 64 + fm * 16 + lr) * BKB;
      const i32x4 lo = *(const i32x4*)(As + base + c0);
      const i32x4 hi = *(const i32x4*)(As + base + c1);
      const i32x8 af = __builtin_shufflevector(lo, hi, 0, 1, 2, 3, 4, 5, 6, 7);
#pragma unroll
      for (int fn = 0; fn < 4; ++fn)
        acc[fm][fn] = __builtin_amdgcn_mfma_scale_f32_16x16x128_f8f6f4(
            af, bf[fn], acc[fm][fn], 0 /*fp8 A*/, 0 /*fp8 B*/,
            0, 0x7f7f7f7f, 0, 0x7f7f7f7f);  // e8m0 127 == scale 1.0
    }
    __syncthreads();
  }

  // ---- epilogue: per-row argmin over this block's 128-wide n range ----
  // C/D layout (shape-determined, dtype-independent): n = lane&15, m = quad*4 + reg
  const int nbase = ntile * BN + wn * 64 + lr;
  float kn[4];
#pragma unroll
  for (int fn = 0; fn < 4; ++fn) kn[fn] = knorm[nbase + fn * 16];

#pragma unroll
  for (int fm = 0; fm < 4; ++fm) {
#pragma unroll
    for (int reg = 0; reg < 4; ++reg) {
      float bv = kn[0] - 2.0f * acc[fm][0][reg];
      int bn = nbase;
#pragma unroll
      for (int fn = 1; fn < 4; ++fn) {
        const float v = kn[fn] - 2.0f * acc[fm][fn][reg];
        if (v < bv) { bv = v; bn = nbase + fn * 16; }
      }
      unsigned long long p =
          ((unsigned long long)orderf(bv) << 32) | (unsigned int)bn;
#pragma unroll
      for (int mask = 1; mask <= 8; mask <<= 1) {
        const unsigned long long q = __shfl_xor(p, mask);
        p = q < p ? q : p;
      }
      if (lr == 0) cand[wn][wm * 64 + fm * 16 + quad * 4 + reg] = p;
    }
  }
  __syncthreads();
  if (tid < BM) {
    const unsigned long long a = cand[0][tid], b = cand[1][tid];
    const unsigned long long m = b < a ? b : a;
    atomicMin(&best[(size_t)mtile * BM + tid], m);
  }
}

// ---------------- finalize: exact fp32 d at winner, ball test, gather ----------------
__global__ void finalize(const unsigned long long* __restrict__ best,
                         const float* __restrict__ keys,
                         const float* __restrict__ values,
                         const int* __restrict__ pi,
                         const float* __restrict__ X,
                         const float* __restrict__ Y,
                         float* __restrict__ out) {
  const int b = blockIdx.x;
  const int t = threadIdx.x;  // 256
  const unsigned long long pk = best[b];
  const int n = (int)(unsigned int)(pk & 0xffffffffull);

  const float4 kv = ((const float4*)(keys + (size_t)n * DIM))[t];
  const float4 qv = (t < 192) ? ((const float4*)(X + (size_t)b * DXV))[t]
                              : ((const float4*)(Y + (size_t)b * DYV))[t - 192];
  const float dx = kv.x - qv.x, dy = kv.y - qv.y, dz = kv.z - qv.z, dw = kv.w - qv.w;
  float s = dx * dx + dy * dy + dz * dz + dw * dw;
  for (int m = 32; m; m >>= 1) s += __shfl_xor(s, m);
  __shared__ float red[4];
  __shared__ float flagS;
  const int lane = t & 63, wave = t >> 6;
  if (lane == 0) red[wave] = s;
  __syncthreads();
  if (t == 0)
    flagS = (red[0] + red[1] + red[2] + red[3] <= THRESH) ? 1.0f : 0.0f;
  __syncthreads();
  const float flag = flagS;
  const int row = pi[n];
  if (t < 192) {
    const float4 v = ((const float4*)(values + (size_t)row * DXV))[t];
    float4 o;
    o.x = v.x * flag; o.y = v.y * flag; o.z = v.z * flag; o.w = v.w * flag;
    ((float4*)(out + (size_t)b * DXV))[t] = o;
  }
}

extern "C" void kernel_launch(void* const* d_in, const int* in_sizes, int n_in,
                              void* d_out, int out_size, void* d_ws, size_t ws_size,
                              hipStream_t stream) {
  const float* keys   = (const float*)d_in[0];
  const float* values = (const float*)d_in[1];
  const int*   pi     = (const int*)d_in[2];
  const float* X      = (const float*)d_in[3];
  const float* Y      = (const float*)d_in[4];
  float* out = (float*)d_out;

  char* ws = (char*)d_ws;
  unsigned char* K8 = (unsigned char*)ws;                          // 64 MB
  unsigned char* Q8 = (unsigned char*)(ws + (size_t)NKEYS * DIM);  // 4 MB
  float* knorm = (float*)(ws + (size_t)NKEYS * DIM + (size_t)BQ * DIM);
  unsigned long long* best =
      (unsigned long long*)(ws + (size_t)NKEYS * DIM + (size_t)BQ * DIM +
                            (size_t)NKEYS * 4);

  hipMemsetAsync(best, 0xFF, (size_t)BQ * 8, stream);
  prep_keys<<<NKEYS, 256, 0, stream>>>(keys, (unsigned int*)K8, knorm);
  prep_q<<<BQ, 256, 0, stream>>>(X, Y, (unsigned int*)Q8);
  gemm_argmin<<<(NKEYS / BN) * (BQ / BM), 256, 0, stream>>>(K8, Q8, knorm, best);
  finalize<<<BQ, 256, 0, stream>>>(best, keys, values, pi, X, Y, out);
}